// Round 2
// baseline (582.756 us; speedup 1.0000x reference)
//
#include <hip/hip_runtime.h>
#include <math.h>

#define B_   1024
#define N_   200
#define NP_  208
#define E_   256
#define R_   256
#define K6_  1536

typedef __attribute__((ext_vector_type(8))) short bf16x8;
typedef __attribute__((ext_vector_type(4))) float f32x4;

__device__ __forceinline__ unsigned short f2bf(float f) {
  unsigned int u = __float_as_uint(f);
  u += 0x7fffu + ((u >> 16) & 1u);          // RNE
  return (unsigned short)(u >> 16);
}

__device__ __forceinline__ float gelu_exact(float x) {
  return 0.5f * x * (1.f + erff(x * 0.70710678118654752f));
}

// ---------------- cast rel_w and sp_w to bf16 in ws ----------------
__global__ __launch_bounds__(256) void k_cast(const float* __restrict__ rel_w,
                                              const float* __restrict__ sp_w,
                                              unsigned short* __restrict__ rw_bf,
                                              unsigned short* __restrict__ spw_bf) {
  int idx = blockIdx.x * 256 + threadIdx.x;
  if (idx < E_ * R_) rw_bf[idx] = f2bf(rel_w[idx]);
  int j = idx - E_ * R_;
  if (j >= 0 && j < 3 * E_ * K6_) spw_bf[j] = f2bf(sp_w[j]);
}

// ------------- q_key = r_emb @ rel_w^T ; cs-gate weights -------------
__global__ __launch_bounds__(256) void k_qkey(
    const float* __restrict__ r_emb, const float* __restrict__ rel_w,
    const float* __restrict__ csq_w, const float* __restrict__ csq_b,
    const float* __restrict__ csl_w, const float* __restrict__ csl_b,
    float* __restrict__ q_key, float* __restrict__ wts) {
  __shared__ __align__(16) float re[8][256];
  __shared__ __align__(16) float sqs[8][256];
  __shared__ float lg[8][3];
  int b0 = blockIdx.x * 8;
  int tid = threadIdx.x;
  for (int i = tid; i < 8 * 256; i += 256)
    re[i >> 8][i & 255] = r_emb[(size_t)(b0 + (i >> 8)) * 256 + (i & 255)];
  __syncthreads();
  int e = tid;
  float qk[8], sv[8];
#pragma unroll
  for (int i = 0; i < 8; ++i) { qk[i] = 0.f; sv[i] = 0.f; }
  const float4* w4 = (const float4*)(rel_w) + (size_t)e * 64;
  const float4* c4 = (const float4*)(csq_w) + (size_t)e * 64;
  for (int r = 0; r < 64; ++r) {
    float4 w = w4[r];
    float4 c = c4[r];
#pragma unroll
    for (int i = 0; i < 8; ++i) {
      float4 x = ((const float4*)re[i])[r];
      qk[i] += w.x * x.x + w.y * x.y + w.z * x.z + w.w * x.w;
      sv[i] += c.x * x.x + c.y * x.y + c.z * x.z + c.w * x.w;
    }
  }
  float cb = csq_b[e];
#pragma unroll
  for (int i = 0; i < 8; ++i) {
    q_key[(size_t)(b0 + i) * 256 + e] = qk[i];
    sqs[i][e] = sv[i] + cb;
  }
  __syncthreads();
  if (tid < 24) {
    int i = tid / 3, k = tid % 3;
    float acc = csl_b[k];
    for (int ee = 0; ee < 256; ++ee) acc += sqs[i][ee] * csl_w[k * 256 + ee];
    lg[i][k] = acc;
  }
  __syncthreads();
  if (tid < 8) {
    float l0 = lg[tid][0], l1 = lg[tid][1], l2 = lg[tid][2];
    float m = fmaxf(l0, fmaxf(l1, l2));
    float e0 = expf(l0 - m), e1 = expf(l1 - m), e2 = expf(l2 - m);
    float inv = 1.f / (e0 + e1 + e2);
    wts[(b0 + tid) * 4 + 0] = e0 * inv;
    wts[(b0 + tid) * 4 + 1] = e1 * inv;
    wts[(b0 + tid) * 4 + 2] = e2 * inv;
  }
}

// ------------- q_proj[s,b,:] = q_key[b,:] @ attn_w[s]^T -------------
__global__ __launch_bounds__(256) void k_qproj(const float* __restrict__ q_key,
                                               const float* __restrict__ attn_w,
                                               float* __restrict__ q_proj) {
  __shared__ __align__(16) float qk[8][256];
  int s = blockIdx.x >> 7;
  int b0 = (blockIdx.x & 127) * 8;
  int tid = threadIdx.x;
  for (int i = tid; i < 2048; i += 256)
    qk[i >> 8][i & 255] = q_key[(size_t)(b0 + (i >> 8)) * 256 + (i & 255)];
  __syncthreads();
  int e = tid;
  float acc[8];
#pragma unroll
  for (int i = 0; i < 8; ++i) acc[i] = 0.f;
  const float4* a4 = (const float4*)(attn_w) + ((size_t)s * 256 + e) * 64;
  for (int r = 0; r < 64; ++r) {
    float4 w = a4[r];
#pragma unroll
    for (int i = 0; i < 8; ++i) {
      float4 x = ((const float4*)qk[i])[r];
      acc[i] += w.x * x.x + w.y * x.y + w.z * x.z + w.w * x.w;
    }
  }
#pragma unroll
  for (int i = 0; i < 8; ++i)
    q_proj[((size_t)s * B_ + b0 + i) * 256 + e] = acc[i];
}

// ------------- t[s,b,r] = sum_e q_proj[s,b,e] * rel_w[e,r] -------------
__global__ __launch_bounds__(256) void k_t(const float* __restrict__ q_proj,
                                           const float* __restrict__ rel_w,
                                           float* __restrict__ t_ws) {
  __shared__ __align__(16) float qp[8][256];
  int s = blockIdx.x >> 7;
  int b0 = (blockIdx.x & 127) * 8;
  int tid = threadIdx.x;
  for (int i = tid; i < 2048; i += 256)
    qp[i >> 8][i & 255] = q_proj[((size_t)s * B_ + b0 + (i >> 8)) * 256 + (i & 255)];
  __syncthreads();
  int r = tid;
  float acc[8];
#pragma unroll
  for (int i = 0; i < 8; ++i) acc[i] = 0.f;
  for (int e = 0; e < 256; ++e) {
    float w = rel_w[(size_t)e * 256 + r];   // coalesced across lanes
#pragma unroll
    for (int i = 0; i < 8; ++i) acc[i] = fmaf(qp[i][e], w, acc[i]);
  }
#pragma unroll
  for (int i = 0; i < 8; ++i)
    t_ws[((size_t)s * B_ + b0 + i) * 256 + r] = acc[i];
}

// ------------- K1: fused msgs-GEMM + masked PNA stats + attention -------------
// block = one b. phase1: logits via t-trick + softmax in LDS.
// phase2: bf16 MFMA msgs tiles (never hit HBM) + stats in registers.
// hist_mask dtype auto-detected (bool-bytes / int32 / float32) per block.
__global__ __launch_bounds__(256, 2) void k1_main(
    const float* __restrict__ nb_rel, const float* __restrict__ delta_t,
    const unsigned char* __restrict__ hm_raw, const float* __restrict__ e_emb,
    const float* __restrict__ p_lt1, const float* __restrict__ p_lt2,
    const float* __restrict__ p_sh, const float* __restrict__ p_lgm,
    const unsigned short* __restrict__ rw_bf, const float* __restrict__ t_ws,
    float* __restrict__ feats) {
  __shared__ __align__(16) struct {
    unsigned int a[64 * 132];   // A-tile: 64 n-rows x 264 bf16 (pad 8 -> 2-way-free banks)
    float t[3][256];
    float c[3][NP_];
    float p[3][NP_];
    float maskf[NP_];
  } sm;
  int b = blockIdx.x;
  int tid = threadIdx.x;
  int lane = tid & 63, wave = tid >> 6;
  int row16 = lane & 15, quad = lane >> 4;

  // ---- mask dtype detection: probe first 512 bytes (safe in all 3 modes) ----
  int hasNZoff = 0, hasFP = 0;
  {
    unsigned char c0 = hm_raw[tid];
    unsigned char c1 = hm_raw[256 + tid];
    if ((tid & 3) != 0 && c0 != 0) {
      hasNZoff = 1;
      if (c0 == 0x3Fu || c0 == 0x80u) hasFP = 1;
    }
    if (((256 + tid) & 3) != 0 && c1 != 0) {
      hasNZoff = 1;
      if (c1 == 0x3Fu || c1 == 0x80u) hasFP = 1;
    }
  }
  int cntNZ = __syncthreads_count(hasNZoff);
  int cntFP = __syncthreads_count(hasFP);
  // mode: 0 = int32, 1 = bool bytes, 2 = float32
  int mmode = (cntNZ == 0) ? 0 : (cntFP > 0 ? 2 : 1);

  float tau1 = expf(p_lt1[0]);
  float tau2 = expf(p_lt2[0]) + tau1;
  float sharp = fminf(fmaxf(p_sh[0], 0.1f), 5.0f);
  float gamma = expf(p_lgm[0]);

  bool mk = false;
  if (tid < NP_) {
    float mf = 0.f, c0 = 0.f, c1 = 0.f, c2 = 0.f;
    if (tid < N_) {
      size_t mi = (size_t)b * N_ + tid;
      if (mmode == 0)      mk = ((const int*)hm_raw)[mi] != 0;
      else if (mmode == 1) mk = hm_raw[mi] != 0;
      else                 mk = ((const float*)hm_raw)[mi] != 0.f;
      float dt = delta_t[mi];
      mf = mk ? 1.f : 0.f;
      float decay = expf(-gamma * fmaxf(dt, 0.f));
      float wf = 1.f / (1.f + expf(sharp * (dt - tau1)));
      float wc = 1.f / (1.f + expf(-sharp * (dt - tau2)));
      float wm = fmaxf(1.f - wf - wc, 0.f);
      c0 = decay * wf; c1 = decay * wm; c2 = decay * wc;
    }
    sm.maskf[tid] = mf;
    sm.c[0][tid] = c0; sm.c[1][tid] = c1; sm.c[2][tid] = c2;
  }
  for (int i = tid; i < 768; i += 256)
    ((float*)sm.t)[i] = t_ws[((size_t)(i >> 8) * B_ + b) * 256 + (i & 255)];

  int cnt = __syncthreads_count(mk ? 1 : 0);
  float nvf = fmaxf((float)cnt, 1.f);
  bool allinv = (cnt == 0);

  // phase 1: attention logits
  if (tid < NP_) {
    if (tid < N_) {
      const float4* row = (const float4*)(nb_rel + ((size_t)b * N_ + tid) * 256);
      const float4* t0 = (const float4*)sm.t[0];
      const float4* t1 = (const float4*)sm.t[1];
      const float4* t2p = (const float4*)sm.t[2];
      float a0 = 0.f, a1 = 0.f, a2 = 0.f;
      for (int r = 0; r < 64; ++r) {
        float4 x = row[r];
        float4 u;
        u = t0[r];  a0 += x.x * u.x + x.y * u.y + x.z * u.z + x.w * u.w;
        u = t1[r];  a1 += x.x * u.x + x.y * u.y + x.z * u.z + x.w * u.w;
        u = t2p[r]; a2 += x.x * u.x + x.y * u.y + x.z * u.z + x.w * u.w;
      }
      bool mkk = sm.maskf[tid] > 0.5f;
      float l0 = sm.c[0][tid] * a0 * 0.0625f;
      float l1 = sm.c[1][tid] * a1 * 0.0625f;
      float l2 = sm.c[2][tid] * a2 * 0.0625f;
      l0 = mkk ? l0 : -1e4f; l1 = mkk ? l1 : -1e4f; l2 = mkk ? l2 : -1e4f;
      if (allinv) { l0 = 0.f; l1 = 0.f; l2 = 0.f; }
      sm.p[0][tid] = l0; sm.p[1][tid] = l1; sm.p[2][tid] = l2;
    } else {
      sm.p[0][tid] = -1e30f; sm.p[1][tid] = -1e30f; sm.p[2][tid] = -1e30f;
    }
  }
  __syncthreads();

  // softmax per scale (waves 0..2); wave 3 copies e_emb into feats tail
  if (wave == 3) {
    for (int i = lane; i < 256; i += 64) {
      float v = e_emb[(size_t)b * 256 + i];
      feats[((size_t)0 * B_ + b) * K6_ + 1280 + i] = v;
      feats[((size_t)1 * B_ + b) * K6_ + 1280 + i] = v;
      feats[((size_t)2 * B_ + b) * K6_ + 1280 + i] = v;
    }
  } else {
    int s = wave;
    float m = -1e30f;
    for (int n = lane; n < NP_; n += 64) m = fmaxf(m, sm.p[s][n]);
#pragma unroll
    for (int o = 32; o >= 1; o >>= 1) m = fmaxf(m, __shfl_xor(m, o, 64));
    float ssum = 0.f;
    for (int n = lane; n < NP_; n += 64) ssum += expf(sm.p[s][n] - m);
#pragma unroll
    for (int o = 32; o >= 1; o >>= 1) ssum += __shfl_xor(ssum, o, 64);
    float inv = 1.f / ssum;
    for (int n = lane; n < NP_; n += 64) sm.p[s][n] = expf(sm.p[s][n] - m) * inv;
  }

  // phase 2: MFMA GEMM over n super-tiles + register stats
  int ebase = wave * 64;
  float s_mean[3][4], s_mx[3][4], s_mn[3][4], s_sq[3][4], s_av[3][4];
#pragma unroll
  for (int s = 0; s < 3; ++s)
#pragma unroll
    for (int t = 0; t < 4; ++t) {
      s_mean[s][t] = 0.f; s_mx[s][t] = -1e30f; s_mn[s][t] = 1e30f;
      s_sq[s][t] = 0.f; s_av[s][t] = 0.f;
    }

  for (int st = 0; st < 4; ++st) {
    int n0 = st * 64;
    int ntc = (st < 3) ? 4 : 1;
    __syncthreads();
    int nf4 = ntc * 16 * 64;
    for (int j = tid; j < nf4; j += 256) {
      int nl = j >> 6;
      int rr = (j & 63) << 2;
      int n = n0 + nl;
      int gn = (n < N_) ? n : (N_ - 1);   // clamp: padded rows masked anyway
      float4 x = *(const float4*)(nb_rel + ((size_t)b * N_ + gn) * 256 + rr);
      unsigned int lo = (unsigned int)f2bf(x.x) | ((unsigned int)f2bf(x.y) << 16);
      unsigned int hi = (unsigned int)f2bf(x.z) | ((unsigned int)f2bf(x.w) << 16);
      int di = nl * 132 + (rr >> 1);
      sm.a[di] = lo;
      sm.a[di + 1] = hi;
    }
    __syncthreads();
    f32x4 acc[4][4];
#pragma unroll
    for (int nt = 0; nt < 4; ++nt)
#pragma unroll
      for (int t = 0; t < 4; ++t)
#pragma unroll
        for (int cc = 0; cc < 4; ++cc) acc[nt][t][cc] = 0.f;
#pragma unroll
    for (int ks = 0; ks < 8; ++ks) {
      bf16x8 bfr[4];
#pragma unroll
      for (int t = 0; t < 4; ++t) {
        int e = ebase + t * 16 + row16;
        int k = ks * 32 + quad * 8;
        bfr[t] = *(const bf16x8*)(rw_bf + (size_t)e * 256 + k);
      }
#pragma unroll
      for (int nt = 0; nt < 4; ++nt) {
        if (nt < ntc) {
          bf16x8 af = *(const bf16x8*)&sm.a[(nt * 16 + row16) * 132 + ks * 16 + quad * 4];
#pragma unroll
          for (int t = 0; t < 4; ++t)
            acc[nt][t] = __builtin_amdgcn_mfma_f32_16x16x32_bf16(af, bfr[t], acc[nt][t], 0, 0, 0);
        }
      }
    }
    // stats: lane owns e = ebase+t*16+row16, n = n0+nt*16+quad*4+rg
    for (int nt = 0; nt < 4; ++nt) {
      if (nt < ntc) {
#pragma unroll
        for (int rg = 0; rg < 4; ++rg) {
          int n = n0 + nt * 16 + quad * 4 + rg;
          float mf = sm.maskf[n];
          bool mb = mf > 0.5f;
#pragma unroll
          for (int s = 0; s < 3; ++s) {
            float cs = sm.c[s][n];
            float ps = sm.p[s][n];
#pragma unroll
            for (int t = 0; t < 4; ++t) {
              float msg = acc[nt][t][rg];
              float v = cs * msg;
              float vm = mb ? v : 0.f;
              s_mean[s][t] += vm;
              s_mx[s][t] = fmaxf(s_mx[s][t], vm);
              s_mn[s][t] = fminf(s_mn[s][t], mb ? v : 1e4f);
              float cv = fminf(fmaxf(vm, -10.f), 10.f);
              s_sq[s][t] = fmaf(cv, cv, s_sq[s][t]);
              s_av[s][t] = fmaf(ps, v, s_av[s][t]);
            }
          }
        }
      }
    }
  }
  // reduce over the 4 lane-quads (n partials) and write feats
#pragma unroll
  for (int s = 0; s < 3; ++s) {
#pragma unroll
    for (int t = 0; t < 4; ++t) {
      float vmean = s_mean[s][t];
      vmean += __shfl_xor(vmean, 16, 64); vmean += __shfl_xor(vmean, 32, 64);
      float vmx = s_mx[s][t];
      vmx = fmaxf(vmx, __shfl_xor(vmx, 16, 64)); vmx = fmaxf(vmx, __shfl_xor(vmx, 32, 64));
      float vmn = s_mn[s][t];
      vmn = fminf(vmn, __shfl_xor(vmn, 16, 64)); vmn = fminf(vmn, __shfl_xor(vmn, 32, 64));
      float vsq = s_sq[s][t];
      vsq += __shfl_xor(vsq, 16, 64); vsq += __shfl_xor(vsq, 32, 64);
      float vav = s_av[s][t];
      vav += __shfl_xor(vav, 16, 64); vav += __shfl_xor(vav, 32, 64);
      if (lane < 16) {
        int e = ebase + t * 16 + lane;
        size_t base = ((size_t)s * B_ + b) * K6_;
        float meanv = vmean / nvf;
        float stdv = sqrtf(fmaxf(vsq / nvf - meanv * meanv, 1e-6f));
        float mnv = fminf(fmaxf(vmn, -1e4f), 1e4f);
        feats[base + e] = meanv;
        feats[base + 256 + e] = vmx;
        feats[base + 512 + e] = mnv;
        feats[base + 768 + e] = stdv;
        feats[base + 1024 + e] = vav;
      }
    }
  }
}

// ------------- K2: h = feats @ sp_w^T + b -> LN -> gelu -> scales -------------
__global__ __launch_bounds__(256) void k2_kernel(
    const float* __restrict__ feats, const unsigned short* __restrict__ spw_bf,
    const float* __restrict__ sp_b, const float* __restrict__ ln_g,
    const float* __restrict__ ln_b, float* __restrict__ scales) {
  __shared__ __align__(16) union {
    unsigned int a[32 * 132];
    float h[32 * 260];
  } sm;
  int s = blockIdx.x >> 5;
  int b0 = (blockIdx.x & 31) * 32;
  int tid = threadIdx.x, lane = tid & 63, wave = tid >> 6;
  int row16 = lane & 15, quad = lane >> 4;
  int ebase = wave * 64;
  f32x4 acc[2][4];
#pragma unroll
  for (int mt = 0; mt < 2; ++mt)
#pragma unroll
    for (int t = 0; t < 4; ++t)
#pragma unroll
      for (int cc = 0; cc < 4; ++cc) acc[mt][t][cc] = 0.f;

  for (int kc = 0; kc < 6; ++kc) {
    __syncthreads();
    for (int j = tid; j < 2048; j += 256) {
      int rw = j >> 6;
      int kk = (j & 63) << 2;
      float4 x = *(const float4*)(feats + ((size_t)s * B_ + b0 + rw) * K6_ + kc * 256 + kk);
      unsigned int lo = (unsigned int)f2bf(x.x) | ((unsigned int)f2bf(x.y) << 16);
      unsigned int hi = (unsigned int)f2bf(x.z) | ((unsigned int)f2bf(x.w) << 16);
      int di = rw * 132 + (kk >> 1);
      sm.a[di] = lo;
      sm.a[di + 1] = hi;
    }
    __syncthreads();
#pragma unroll
    for (int ks = 0; ks < 8; ++ks) {
      bf16x8 bfr[4];
#pragma unroll
      for (int t = 0; t < 4; ++t) {
        int e = ebase + t * 16 + row16;
        int k = kc * 256 + ks * 32 + quad * 8;
        bfr[t] = *(const bf16x8*)(spw_bf + ((size_t)s * E_ + e) * K6_ + k);
      }
#pragma unroll
      for (int mt = 0; mt < 2; ++mt) {
        bf16x8 af = *(const bf16x8*)&sm.a[(mt * 16 + row16) * 132 + ks * 16 + quad * 4];
#pragma unroll
        for (int t = 0; t < 4; ++t)
          acc[mt][t] = __builtin_amdgcn_mfma_f32_16x16x32_bf16(af, bfr[t], acc[mt][t], 0, 0, 0);
      }
    }
  }
  __syncthreads();
#pragma unroll
  for (int mt = 0; mt < 2; ++mt)
#pragma unroll
    for (int t = 0; t < 4; ++t)
#pragma unroll
      for (int rg = 0; rg < 4; ++rg) {
        int rw = mt * 16 + quad * 4 + rg;
        int e = ebase + t * 16 + row16;
        sm.h[rw * 260 + e] = acc[mt][t][rg] + sp_b[s * 256 + e];
      }
  __syncthreads();
  for (int rr = 0; rr < 8; ++rr) {
    int rw = wave * 8 + rr;
    float4 x = *(const float4*)&sm.h[rw * 260 + lane * 4];
    float sum = x.x + x.y + x.z + x.w;
    float sq = x.x * x.x + x.y * x.y + x.z * x.z + x.w * x.w;
#pragma unroll
    for (int o = 32; o >= 1; o >>= 1) {
      sum += __shfl_xor(sum, o, 64);
      sq += __shfl_xor(sq, o, 64);
    }
    float mu = sum * (1.f / 256.f);
    float var = sq * (1.f / 256.f) - mu * mu;
    float rstd = rsqrtf(var + 1e-5f);
    float4 g = *(const float4*)(ln_g + s * 256 + lane * 4);
    float4 bb = *(const float4*)(ln_b + s * 256 + lane * 4);
    float4 o4;
    o4.x = gelu_exact((x.x - mu) * rstd * g.x + bb.x);
    o4.y = gelu_exact((x.y - mu) * rstd * g.y + bb.y);
    o4.z = gelu_exact((x.z - mu) * rstd * g.z + bb.z);
    o4.w = gelu_exact((x.w - mu) * rstd * g.w + bb.w);
    *(float4*)(scales + ((size_t)s * B_ + b0 + rw) * 256 + lane * 4) = o4;
  }
}

// ------------- K3: out = LN(sum_s w[b,s]*scales[s,b,:]) -------------
__global__ __launch_bounds__(256) void k3_kernel(
    const float* __restrict__ scales, const float* __restrict__ wts,
    const float* __restrict__ on_g, const float* __restrict__ on_b,
    float* __restrict__ out) {
  __shared__ float rs[4], rq[4];
  int b = blockIdx.x, tid = threadIdx.x, lane = tid & 63, wave = tid >> 6;
  float w0 = wts[b * 4 + 0], w1 = wts[b * 4 + 1], w2 = wts[b * 4 + 2];
  float o = w0 * scales[((size_t)0 * B_ + b) * 256 + tid] +
            w1 * scales[((size_t)1 * B_ + b) * 256 + tid] +
            w2 * scales[((size_t)2 * B_ + b) * 256 + tid];
  float sum = o, sq = o * o;
#pragma unroll
  for (int off = 32; off >= 1; off >>= 1) {
    sum += __shfl_xor(sum, off, 64);
    sq += __shfl_xor(sq, off, 64);
  }
  if (lane == 0) { rs[wave] = sum; rq[wave] = sq; }
  __syncthreads();
  float ts = rs[0] + rs[1] + rs[2] + rs[3];
  float tq = rq[0] + rq[1] + rq[2] + rq[3];
  float mu = ts * (1.f / 256.f);
  float var = tq * (1.f / 256.f) - mu * mu;
  float rstd = rsqrtf(var + 1e-5f);
  out[(size_t)b * 256 + tid] = (o - mu) * rstd * on_g[tid] + on_b[tid];
}

extern "C" void kernel_launch(void* const* d_in, const int* in_sizes, int n_in,
                              void* d_out, int out_size, void* d_ws, size_t ws_size,
                              hipStream_t stream) {
  const float* e_emb   = (const float*)d_in[0];
  const float* nb_rel  = (const float*)d_in[1];
  const float* delta_t = (const float*)d_in[2];
  const float* r_emb   = (const float*)d_in[3];
  const unsigned char* hist_mask = (const unsigned char*)d_in[4]; // dtype auto-detected in k1
  const float* rel_w   = (const float*)d_in[5];
  const float* lt1     = (const float*)d_in[6];
  const float* lt2     = (const float*)d_in[7];
  const float* shp     = (const float*)d_in[8];
  const float* lgm     = (const float*)d_in[9];
  const float* attn_w  = (const float*)d_in[10];
  const float* sp_w    = (const float*)d_in[11];
  const float* sp_b    = (const float*)d_in[12];
  const float* ln_g    = (const float*)d_in[13];
  const float* ln_b    = (const float*)d_in[14];
  const float* csq_w   = (const float*)d_in[15];
  const float* csq_b   = (const float*)d_in[16];
  const float* csl_w   = (const float*)d_in[17];
  const float* csl_b   = (const float*)d_in[18];
  const float* on_g    = (const float*)d_in[19];
  const float* on_b    = (const float*)d_in[20];
  float* out = (float*)d_out;

  char* ws = (char*)d_ws;
  unsigned short* rw_bf  = (unsigned short*)(ws + 0);        // 131072 B
  unsigned short* spw_bf = (unsigned short*)(ws + 131072);   // 2359296 B
  float* q_key  = (float*)(ws + 2490368);                    // 1 MB
  float* q_proj = (float*)(ws + 3538944);                    // 3 MB
  float* t_ws   = (float*)(ws + 6684672);                    // 3 MB
  float* wts    = (float*)(ws + 9830400);                    // 16 KB
  float* feats  = (float*)(ws + 9846784);                    // 18.87 MB
  float* scales = (float*)(ws + 28721152);                   // 3 MB  (total ~30.4 MB)

  hipLaunchKernelGGL(k_cast, dim3(4864), dim3(256), 0, stream, rel_w, sp_w, rw_bf, spw_bf);
  hipLaunchKernelGGL(k_qkey, dim3(128), dim3(256), 0, stream, r_emb, rel_w, csq_w, csq_b,
                     csl_w, csl_b, q_key, wts);
  hipLaunchKernelGGL(k_qproj, dim3(384), dim3(256), 0, stream, q_key, attn_w, q_proj);
  hipLaunchKernelGGL(k_t, dim3(384), dim3(256), 0, stream, q_proj, rel_w, t_ws);
  hipLaunchKernelGGL(k1_main, dim3(1024), dim3(256), 0, stream, nb_rel, delta_t, hist_mask,
                     e_emb, lt1, lt2, shp, lgm, rw_bf, t_ws, feats);
  hipLaunchKernelGGL(k2_kernel, dim3(96), dim3(256), 0, stream, feats, spw_bf, sp_b,
                     ln_g, ln_b, scales);
  hipLaunchKernelGGL(k3_kernel, dim3(1024), dim3(256), 0, stream, scales, wts, on_g, on_b, out);
}

// Round 3
// 537.773 us; speedup vs baseline: 1.0836x; 1.0836x over previous
//
#include <hip/hip_runtime.h>
#include <math.h>

#define B_   1024
#define N_   200
#define NR_  208      // padded rows (13 x 16)
#define NT_  13
#define E_   256
#define R_   256
#define K6_  1536

typedef __attribute__((ext_vector_type(8))) short bf16x8;
typedef __attribute__((ext_vector_type(4))) float f32x4;

__device__ __forceinline__ unsigned short f2bf(float f) {
  unsigned int u = __float_as_uint(f);
  u += 0x7fffu + ((u >> 16) & 1u);          // RNE
  return (unsigned short)(u >> 16);
}

__device__ __forceinline__ float gelu_exact(float x) {
  return 0.5f * x * (1.f + erff(x * 0.70710678118654752f));
}

// ---------------- cast rel_w and sp_w to bf16 in ws ----------------
__global__ __launch_bounds__(256) void k_cast(const float* __restrict__ rel_w,
                                              const float* __restrict__ sp_w,
                                              unsigned short* __restrict__ rw_bf,
                                              unsigned short* __restrict__ spw_bf) {
  int idx = blockIdx.x * 256 + threadIdx.x;
  if (idx < E_ * R_) rw_bf[idx] = f2bf(rel_w[idx]);
  int j = idx - E_ * R_;
  if (j >= 0 && j < 3 * E_ * K6_) spw_bf[j] = f2bf(sp_w[j]);
}

// ------------- q_key = r_emb @ rel_w^T ; cs-gate weights -------------
__global__ __launch_bounds__(256) void k_qkey(
    const float* __restrict__ r_emb, const float* __restrict__ rel_w,
    const float* __restrict__ csq_w, const float* __restrict__ csq_b,
    const float* __restrict__ csl_w, const float* __restrict__ csl_b,
    float* __restrict__ q_key, float* __restrict__ wts) {
  __shared__ __align__(16) float re[8][256];
  __shared__ __align__(16) float sqs[8][256];
  __shared__ float lg[8][3];
  int b0 = blockIdx.x * 8;
  int tid = threadIdx.x;
  for (int i = tid; i < 8 * 256; i += 256)
    re[i >> 8][i & 255] = r_emb[(size_t)(b0 + (i >> 8)) * 256 + (i & 255)];
  __syncthreads();
  int e = tid;
  float qk[8], sv[8];
#pragma unroll
  for (int i = 0; i < 8; ++i) { qk[i] = 0.f; sv[i] = 0.f; }
  const float4* w4 = (const float4*)(rel_w) + (size_t)e * 64;
  const float4* c4 = (const float4*)(csq_w) + (size_t)e * 64;
  for (int r = 0; r < 64; ++r) {
    float4 w = w4[r];
    float4 c = c4[r];
#pragma unroll
    for (int i = 0; i < 8; ++i) {
      float4 x = ((const float4*)re[i])[r];
      qk[i] += w.x * x.x + w.y * x.y + w.z * x.z + w.w * x.w;
      sv[i] += c.x * x.x + c.y * x.y + c.z * x.z + c.w * x.w;
    }
  }
  float cb = csq_b[e];
#pragma unroll
  for (int i = 0; i < 8; ++i) {
    q_key[(size_t)(b0 + i) * 256 + e] = qk[i];
    sqs[i][e] = sv[i] + cb;
  }
  __syncthreads();
  if (tid < 24) {
    int i = tid / 3, k = tid % 3;
    float acc = csl_b[k];
    for (int ee = 0; ee < 256; ++ee) acc += sqs[i][ee] * csl_w[k * 256 + ee];
    lg[i][k] = acc;
  }
  __syncthreads();
  if (tid < 8) {
    float l0 = lg[tid][0], l1 = lg[tid][1], l2 = lg[tid][2];
    float m = fmaxf(l0, fmaxf(l1, l2));
    float e0 = expf(l0 - m), e1 = expf(l1 - m), e2 = expf(l2 - m);
    float inv = 1.f / (e0 + e1 + e2);
    wts[(b0 + tid) * 4 + 0] = e0 * inv;
    wts[(b0 + tid) * 4 + 1] = e1 * inv;
    wts[(b0 + tid) * 4 + 2] = e2 * inv;
  }
}

// ------------- q_proj[s,b,:] = q_key[b,:] @ attn_w[s]^T -------------
__global__ __launch_bounds__(256) void k_qproj(const float* __restrict__ q_key,
                                               const float* __restrict__ attn_w,
                                               float* __restrict__ q_proj) {
  __shared__ __align__(16) float qk[8][256];
  int s = blockIdx.x >> 7;
  int b0 = (blockIdx.x & 127) * 8;
  int tid = threadIdx.x;
  for (int i = tid; i < 2048; i += 256)
    qk[i >> 8][i & 255] = q_key[(size_t)(b0 + (i >> 8)) * 256 + (i & 255)];
  __syncthreads();
  int e = tid;
  float acc[8];
#pragma unroll
  for (int i = 0; i < 8; ++i) acc[i] = 0.f;
  const float4* a4 = (const float4*)(attn_w) + ((size_t)s * 256 + e) * 64;
  for (int r = 0; r < 64; ++r) {
    float4 w = a4[r];
#pragma unroll
    for (int i = 0; i < 8; ++i) {
      float4 x = ((const float4*)qk[i])[r];
      acc[i] += w.x * x.x + w.y * x.y + w.z * x.z + w.w * x.w;
    }
  }
#pragma unroll
  for (int i = 0; i < 8; ++i)
    q_proj[((size_t)s * B_ + b0 + i) * 256 + e] = acc[i];
}

// ------------- t[s,b,r] = sum_e q_proj[s,b,e] * rel_w[e,r] -------------
__global__ __launch_bounds__(256) void k_t(const float* __restrict__ q_proj,
                                           const float* __restrict__ rel_w,
                                           float* __restrict__ t_ws) {
  __shared__ __align__(16) float qp[8][256];
  int s = blockIdx.x >> 7;
  int b0 = (blockIdx.x & 127) * 8;
  int tid = threadIdx.x;
  for (int i = tid; i < 2048; i += 256)
    qp[i >> 8][i & 255] = q_proj[((size_t)s * B_ + b0 + (i >> 8)) * 256 + (i & 255)];
  __syncthreads();
  int r = tid;
  float acc[8];
#pragma unroll
  for (int i = 0; i < 8; ++i) acc[i] = 0.f;
  for (int e = 0; e < 256; ++e) {
    float w = rel_w[(size_t)e * 256 + r];   // coalesced across lanes
#pragma unroll
    for (int i = 0; i < 8; ++i) acc[i] = fmaf(qp[i][e], w, acc[i]);
  }
#pragma unroll
  for (int i = 0; i < 8; ++i)
    t_ws[((size_t)s * B_ + b0 + i) * 256 + r] = acc[i];
}

// ------------- K1: single-pass fused msgs-GEMM + PNA stats + attention -------
// 512 threads, block = one b. Full 208x256 bf16 tile resident in LDS.
// Staging loop: wave-per-row coalesced loads, logit dots fused on fp32 regs.
__global__ __launch_bounds__(512, 2) void k1_main(
    const float* __restrict__ nb_rel, const float* __restrict__ delta_t,
    const unsigned char* __restrict__ hm_raw, const float* __restrict__ e_emb,
    const float* __restrict__ p_lt1, const float* __restrict__ p_lt2,
    const float* __restrict__ p_sh, const float* __restrict__ p_lgm,
    const unsigned short* __restrict__ rw_bf, const float* __restrict__ t_ws,
    unsigned short* __restrict__ feats) {
  __shared__ __align__(16) struct {
    unsigned int a[NR_ * 132];   // bf16 tile, row stride 264 bf16 (256 data + 8 pad)
    float araw[3][NR_];
    float c[3][NR_];
    float p[3][NR_];
    float nmeta[NR_][9];         // cm0,cm1,cm2,off,q0,q1,q2,maskf,pad (stride 9: no quad conflicts)
  } sm;
  int b = blockIdx.x;
  int tid = threadIdx.x;
  int lane = tid & 63, wave = tid >> 6;
  int row16 = lane & 15, quad = lane >> 4;

  // t fragments (lane owns r = lane*4 .. lane*4+3)
  float4 tf0 = *(const float4*)&t_ws[((size_t)0 * B_ + b) * 256 + lane * 4];
  float4 tf1 = *(const float4*)&t_ws[((size_t)1 * B_ + b) * 256 + lane * 4];
  float4 tf2 = *(const float4*)&t_ws[((size_t)2 * B_ + b) * 256 + lane * 4];

  // ---- mask dtype detection: probe first 512 bytes ----
  int hasNZoff = 0, hasFP = 0;
  {
    unsigned char cc = hm_raw[tid];
    if ((tid & 3) != 0 && cc != 0) {
      hasNZoff = 1;
      if (cc == 0x3Fu || cc == 0x80u) hasFP = 1;
    }
  }
  int cntNZ = __syncthreads_count(hasNZoff);
  int cntFP = __syncthreads_count(hasFP);
  int mmode = (cntNZ == 0) ? 0 : (cntFP > 0 ? 2 : 1);  // 0=int32 1=bool 2=f32

  float tau1 = expf(p_lt1[0]);
  float tau2 = expf(p_lt2[0]) + tau1;
  float sharp = fminf(fmaxf(p_sh[0], 0.1f), 5.0f);
  float gamma = expf(p_lgm[0]);

  bool mk = false;
  if (tid < NR_) {
    float mf = 0.f, c0 = 0.f, c1 = 0.f, c2 = 0.f;
    if (tid < N_) {
      size_t mi = (size_t)b * N_ + tid;
      if (mmode == 0)      mk = ((const int*)hm_raw)[mi] != 0;
      else if (mmode == 1) mk = hm_raw[mi] != 0;
      else                 mk = ((const float*)hm_raw)[mi] != 0.f;
      float dt = delta_t[mi];
      mf = mk ? 1.f : 0.f;
      float decay = expf(-gamma * fmaxf(dt, 0.f));
      float wf = 1.f / (1.f + expf(sharp * (dt - tau1)));
      float wc = 1.f / (1.f + expf(-sharp * (dt - tau2)));
      float wm = fmaxf(1.f - wf - wc, 0.f);
      c0 = decay * wf; c1 = decay * wm; c2 = decay * wc;
    }
    sm.c[0][tid] = c0; sm.c[1][tid] = c1; sm.c[2][tid] = c2;
    sm.nmeta[tid][0] = mf * c0;
    sm.nmeta[tid][1] = mf * c1;
    sm.nmeta[tid][2] = mf * c2;
    sm.nmeta[tid][3] = mk ? 0.f : 1e4f;
    sm.nmeta[tid][7] = mf;
  }
  int cnt = __syncthreads_count(mk ? 1 : 0);
  float nvf = fmaxf((float)cnt, 1.f);
  bool allinv = (cnt == 0);

  // ---- staging + fused logit dots: wave w handles rows w, w+8, ... ----
  {
    const float* src = nb_rel + (size_t)b * N_ * 256;
    int n0 = wave;
    int g0 = (n0 < N_) ? n0 : (N_ - 1);
    float4 x = *(const float4*)(src + (size_t)g0 * 256 + lane * 4);
    for (int i = 0; i < 26; ++i) {
      int ncur = i * 8 + wave;
      float4 xn;
      if (i < 25) {
        int nn = (i + 1) * 8 + wave;
        int gn = (nn < N_) ? nn : (N_ - 1);
        xn = *(const float4*)(src + (size_t)gn * 256 + lane * 4);
      }
      float d0 = x.x * tf0.x + x.y * tf0.y + x.z * tf0.z + x.w * tf0.w;
      float d1 = x.x * tf1.x + x.y * tf1.y + x.z * tf1.z + x.w * tf1.w;
      float d2 = x.x * tf2.x + x.y * tf2.y + x.z * tf2.z + x.w * tf2.w;
#pragma unroll
      for (int o = 1; o < 64; o <<= 1) {
        d0 += __shfl_xor(d0, o, 64);
        d1 += __shfl_xor(d1, o, 64);
        d2 += __shfl_xor(d2, o, 64);
      }
      if (lane < 3) sm.araw[lane][ncur] = (lane == 0) ? d0 : ((lane == 1) ? d1 : d2);
      uint2 pk;
      pk.x = (unsigned int)f2bf(x.x) | ((unsigned int)f2bf(x.y) << 16);
      pk.y = (unsigned int)f2bf(x.z) | ((unsigned int)f2bf(x.w) << 16);
      *(uint2*)&sm.a[ncur * 132 + lane * 2] = pk;
      x = xn;
    }
  }

  // B-fragment preload (global, L2-hot; no LDS dependency)
  bf16x8 bfr[2][8];
#pragma unroll
  for (int t = 0; t < 2; ++t) {
    int e = wave * 32 + t * 16 + row16;
#pragma unroll
    for (int ks = 0; ks < 8; ++ks)
      bfr[t][ks] = *(const bf16x8*)(rw_bf + (size_t)e * 256 + ks * 32 + quad * 8);
  }
  __syncthreads();

  // ---- logits from raw dots ----
  if (tid < NR_) {
    float l0 = -1e30f, l1 = -1e30f, l2 = -1e30f;
    if (tid < N_) {
      bool mkk = sm.nmeta[tid][7] > 0.5f;
      l0 = sm.c[0][tid] * sm.araw[0][tid] * 0.0625f;
      l1 = sm.c[1][tid] * sm.araw[1][tid] * 0.0625f;
      l2 = sm.c[2][tid] * sm.araw[2][tid] * 0.0625f;
      l0 = mkk ? l0 : -1e4f; l1 = mkk ? l1 : -1e4f; l2 = mkk ? l2 : -1e4f;
      if (allinv) { l0 = 0.f; l1 = 0.f; l2 = 0.f; }
    }
    sm.p[0][tid] = l0; sm.p[1][tid] = l1; sm.p[2][tid] = l2;
  }
  __syncthreads();

  // ---- softmax (waves 0-2) + e_emb tail copy (wave 3) ----
  if (wave < 3) {
    int s = wave;
    float m = -1e30f;
    for (int n = lane; n < NR_; n += 64) m = fmaxf(m, sm.p[s][n]);
#pragma unroll
    for (int o = 32; o >= 1; o >>= 1) m = fmaxf(m, __shfl_xor(m, o, 64));
    float ssum = 0.f;
    for (int n = lane; n < NR_; n += 64) ssum += expf(sm.p[s][n] - m);
#pragma unroll
    for (int o = 32; o >= 1; o >>= 1) ssum += __shfl_xor(ssum, o, 64);
    float inv = 1.f / ssum;
    for (int n = lane; n < NR_; n += 64) {
      float pv = expf(sm.p[s][n] - m) * inv;
      sm.nmeta[n][4 + s] = pv * sm.c[s][n];
    }
  } else if (wave == 3) {
    for (int i = lane; i < 256; i += 64) {
      unsigned short v = f2bf(e_emb[(size_t)b * 256 + i]);
      feats[((size_t)0 * B_ + b) * K6_ + 1280 + i] = v;
      feats[((size_t)1 * B_ + b) * K6_ + 1280 + i] = v;
      feats[((size_t)2 * B_ + b) * K6_ + 1280 + i] = v;
    }
  }
  __syncthreads();

  // ---- MFMA GEMM over all 13 n-tiles + register stats (wave owns 32 e-cols) ----
  float s_mean[3][2], s_mx[3][2], s_mn[3][2], s_sq[3][2], s_av[3][2];
#pragma unroll
  for (int s = 0; s < 3; ++s)
#pragma unroll
    for (int t = 0; t < 2; ++t) {
      s_mean[s][t] = 0.f; s_mx[s][t] = -1e30f; s_mn[s][t] = 1e30f;
      s_sq[s][t] = 0.f; s_av[s][t] = 0.f;
    }

  for (int nt = 0; nt < NT_; ++nt) {
    f32x4 acc[2];
#pragma unroll
    for (int t = 0; t < 2; ++t)
#pragma unroll
      for (int cc = 0; cc < 4; ++cc) acc[t][cc] = 0.f;
#pragma unroll
    for (int ks = 0; ks < 8; ++ks) {
      bf16x8 af = *(const bf16x8*)&sm.a[(nt * 16 + row16) * 132 + ks * 16 + quad * 4];
      acc[0] = __builtin_amdgcn_mfma_f32_16x16x32_bf16(af, bfr[0][ks], acc[0], 0, 0, 0);
      acc[1] = __builtin_amdgcn_mfma_f32_16x16x32_bf16(af, bfr[1][ks], acc[1], 0, 0, 0);
    }
    int nb = nt * 16 + quad * 4;
#pragma unroll
    for (int rg = 0; rg < 4; ++rg) {
      int n = nb + rg;
      float cmv[3], qv[3];
      cmv[0] = sm.nmeta[n][0]; cmv[1] = sm.nmeta[n][1]; cmv[2] = sm.nmeta[n][2];
      float off = sm.nmeta[n][3];
      qv[0] = sm.nmeta[n][4]; qv[1] = sm.nmeta[n][5]; qv[2] = sm.nmeta[n][6];
#pragma unroll
      for (int t = 0; t < 2; ++t) {
        float m = acc[t][rg];
#pragma unroll
        for (int s = 0; s < 3; ++s) {
          float vm = cmv[s] * m;                 // masked c_s * msg (0 if masked)
          s_mean[s][t] += vm;
          s_mx[s][t] = fmaxf(s_mx[s][t], vm);
          float mnc = fmaf(cmv[s], m, off);      // valid: c*m ; masked: 1e4
          s_mn[s][t] = fminf(s_mn[s][t], mnc);
          float cv = fminf(fmaxf(vm, -10.f), 10.f);
          s_sq[s][t] = fmaf(cv, cv, s_sq[s][t]);
          s_av[s][t] = fmaf(qv[s], m, s_av[s][t]); // p_s*c_s*msg (allinv-safe)
        }
      }
    }
  }

  // ---- reduce across quads, write feats (bf16) ----
#pragma unroll
  for (int s = 0; s < 3; ++s) {
#pragma unroll
    for (int t = 0; t < 2; ++t) {
      float vmean = s_mean[s][t];
      vmean += __shfl_xor(vmean, 16, 64); vmean += __shfl_xor(vmean, 32, 64);
      float vmx = s_mx[s][t];
      vmx = fmaxf(vmx, __shfl_xor(vmx, 16, 64)); vmx = fmaxf(vmx, __shfl_xor(vmx, 32, 64));
      float vmn = s_mn[s][t];
      vmn = fminf(vmn, __shfl_xor(vmn, 16, 64)); vmn = fminf(vmn, __shfl_xor(vmn, 32, 64));
      float vsq = s_sq[s][t];
      vsq += __shfl_xor(vsq, 16, 64); vsq += __shfl_xor(vsq, 32, 64);
      float vav = s_av[s][t];
      vav += __shfl_xor(vav, 16, 64); vav += __shfl_xor(vav, 32, 64);
      if (lane < 16) {
        int e = wave * 32 + t * 16 + lane;
        size_t base = ((size_t)s * B_ + b) * K6_;
        float meanv = vmean / nvf;
        float stdv = sqrtf(fmaxf(vsq / nvf - meanv * meanv, 1e-6f));
        float mnv = fminf(fmaxf(vmn, -1e4f), 1e4f);
        feats[base + e] = f2bf(meanv);
        feats[base + 256 + e] = f2bf(vmx);
        feats[base + 512 + e] = f2bf(mnv);
        feats[base + 768 + e] = f2bf(stdv);
        feats[base + 1024 + e] = f2bf(vav);
      }
    }
  }
}

// ------------- K2: h = feats(bf16) @ sp_w^T + b -> LN -> gelu -> scales -------
__global__ __launch_bounds__(256) void k2_kernel(
    const unsigned short* __restrict__ feats, const unsigned short* __restrict__ spw_bf,
    const float* __restrict__ sp_b, const float* __restrict__ ln_g,
    const float* __restrict__ ln_b, float* __restrict__ scales) {
  __shared__ __align__(16) union {
    unsigned int a[32 * 132];
    float h[32 * 260];
  } sm;
  int s = blockIdx.x >> 5;
  int b0 = (blockIdx.x & 31) * 32;
  int tid = threadIdx.x, lane = tid & 63, wave = tid >> 6;
  int row16 = lane & 15, quad = lane >> 4;
  int ebase = wave * 64;
  f32x4 acc[2][4];
#pragma unroll
  for (int mt = 0; mt < 2; ++mt)
#pragma unroll
    for (int t = 0; t < 4; ++t)
#pragma unroll
      for (int cc = 0; cc < 4; ++cc) acc[mt][t][cc] = 0.f;

  for (int kc = 0; kc < 6; ++kc) {
    __syncthreads();
    for (int j = tid; j < 1024; j += 256) {
      int rw = j >> 5, ck = j & 31;
      bf16x8 v = *(const bf16x8*)(feats + ((size_t)s * B_ + b0 + rw) * K6_ + kc * 256 + ck * 8);
      *(bf16x8*)((unsigned short*)&sm.a[rw * 132] + ck * 8) = v;
    }
    __syncthreads();
#pragma unroll
    for (int ks = 0; ks < 8; ++ks) {
      bf16x8 bfr[4];
#pragma unroll
      for (int t = 0; t < 4; ++t) {
        int e = ebase + t * 16 + row16;
        int k = kc * 256 + ks * 32 + quad * 8;
        bfr[t] = *(const bf16x8*)(spw_bf + ((size_t)s * E_ + e) * K6_ + k);
      }
#pragma unroll
      for (int mt = 0; mt < 2; ++mt) {
        bf16x8 af = *(const bf16x8*)&sm.a[(mt * 16 + row16) * 132 + ks * 16 + quad * 4];
#pragma unroll
        for (int t = 0; t < 4; ++t)
          acc[mt][t] = __builtin_amdgcn_mfma_f32_16x16x32_bf16(af, bfr[t], acc[mt][t], 0, 0, 0);
      }
    }
  }
  __syncthreads();
#pragma unroll
  for (int mt = 0; mt < 2; ++mt)
#pragma unroll
    for (int t = 0; t < 4; ++t)
#pragma unroll
      for (int rg = 0; rg < 4; ++rg) {
        int rw = mt * 16 + quad * 4 + rg;
        int e = ebase + t * 16 + row16;
        sm.h[rw * 260 + e] = acc[mt][t][rg] + sp_b[s * 256 + e];
      }
  __syncthreads();
  for (int rr = 0; rr < 8; ++rr) {
    int rw = wave * 8 + rr;
    float4 x = *(const float4*)&sm.h[rw * 260 + lane * 4];
    float sum = x.x + x.y + x.z + x.w;
    float sq = x.x * x.x + x.y * x.y + x.z * x.z + x.w * x.w;
#pragma unroll
    for (int o = 32; o >= 1; o >>= 1) {
      sum += __shfl_xor(sum, o, 64);
      sq += __shfl_xor(sq, o, 64);
    }
    float mu = sum * (1.f / 256.f);
    float var = sq * (1.f / 256.f) - mu * mu;
    float rstd = rsqrtf(var + 1e-5f);
    float4 g = *(const float4*)(ln_g + s * 256 + lane * 4);
    float4 bb = *(const float4*)(ln_b + s * 256 + lane * 4);
    float4 o4;
    o4.x = gelu_exact((x.x - mu) * rstd * g.x + bb.x);
    o4.y = gelu_exact((x.y - mu) * rstd * g.y + bb.y);
    o4.z = gelu_exact((x.z - mu) * rstd * g.z + bb.z);
    o4.w = gelu_exact((x.w - mu) * rstd * g.w + bb.w);
    *(float4*)(scales + ((size_t)s * B_ + b0 + rw) * 256 + lane * 4) = o4;
  }
}

// ------------- K3: out = LN(sum_s w[b,s]*scales[s,b,:]) -------------
__global__ __launch_bounds__(256) void k3_kernel(
    const float* __restrict__ scales, const float* __restrict__ wts,
    const float* __restrict__ on_g, const float* __restrict__ on_b,
    float* __restrict__ out) {
  __shared__ float rs[4], rq[4];
  int b = blockIdx.x, tid = threadIdx.x, lane = tid & 63, wave = tid >> 6;
  float w0 = wts[b * 4 + 0], w1 = wts[b * 4 + 1], w2 = wts[b * 4 + 2];
  float o = w0 * scales[((size_t)0 * B_ + b) * 256 + tid] +
            w1 * scales[((size_t)1 * B_ + b) * 256 + tid] +
            w2 * scales[((size_t)2 * B_ + b) * 256 + tid];
  float sum = o, sq = o * o;
#pragma unroll
  for (int off = 32; off >= 1; off >>= 1) {
    sum += __shfl_xor(sum, off, 64);
    sq += __shfl_xor(sq, off, 64);
  }
  if (lane == 0) { rs[wave] = sum; rq[wave] = sq; }
  __syncthreads();
  float ts = rs[0] + rs[1] + rs[2] + rs[3];
  float tq = rq[0] + rq[1] + rq[2] + rq[3];
  float mu = ts * (1.f / 256.f);
  float var = tq * (1.f / 256.f) - mu * mu;
  float rstd = rsqrtf(var + 1e-5f);
  out[(size_t)b * 256 + tid] = (o - mu) * rstd * on_g[tid] + on_b[tid];
}

extern "C" void kernel_launch(void* const* d_in, const int* in_sizes, int n_in,
                              void* d_out, int out_size, void* d_ws, size_t ws_size,
                              hipStream_t stream) {
  const float* e_emb   = (const float*)d_in[0];
  const float* nb_rel  = (const float*)d_in[1];
  const float* delta_t = (const float*)d_in[2];
  const float* r_emb   = (const float*)d_in[3];
  const unsigned char* hist_mask = (const unsigned char*)d_in[4]; // dtype auto-detected in k1
  const float* rel_w   = (const float*)d_in[5];
  const float* lt1     = (const float*)d_in[6];
  const float* lt2     = (const float*)d_in[7];
  const float* shp     = (const float*)d_in[8];
  const float* lgm     = (const float*)d_in[9];
  const float* attn_w  = (const float*)d_in[10];
  const float* sp_w    = (const float*)d_in[11];
  const float* sp_b    = (const float*)d_in[12];
  const float* ln_g    = (const float*)d_in[13];
  const float* ln_b    = (const float*)d_in[14];
  const float* csq_w   = (const float*)d_in[15];
  const float* csq_b   = (const float*)d_in[16];
  const float* csl_w   = (const float*)d_in[17];
  const float* csl_b   = (const float*)d_in[18];
  const float* on_g    = (const float*)d_in[19];
  const float* on_b    = (const float*)d_in[20];
  float* out = (float*)d_out;

  char* ws = (char*)d_ws;
  unsigned short* rw_bf  = (unsigned short*)(ws + 0);        // 131072 B
  unsigned short* spw_bf = (unsigned short*)(ws + 131072);   // 2359296 B
  float* q_key  = (float*)(ws + 2490368);                    // 1 MB
  float* q_proj = (float*)(ws + 3538944);                    // 3 MB
  float* t_ws   = (float*)(ws + 6684672);                    // 3 MB
  float* wts    = (float*)(ws + 9830400);                    // 16 KB
  unsigned short* feats = (unsigned short*)(ws + 9846784);   // 9.44 MB (bf16)
  float* scales = (float*)(ws + 19283968);                   // 3 MB (total ~22.4 MB)

  hipLaunchKernelGGL(k_cast, dim3(4864), dim3(256), 0, stream, rel_w, sp_w, rw_bf, spw_bf);
  hipLaunchKernelGGL(k_qkey, dim3(128), dim3(256), 0, stream, r_emb, rel_w, csq_w, csq_b,
                     csl_w, csl_b, q_key, wts);
  hipLaunchKernelGGL(k_qproj, dim3(384), dim3(256), 0, stream, q_key, attn_w, q_proj);
  hipLaunchKernelGGL(k_t, dim3(384), dim3(256), 0, stream, q_proj, rel_w, t_ws);
  hipLaunchKernelGGL(k1_main, dim3(1024), dim3(512), 0, stream, nb_rel, delta_t, hist_mask,
                     e_emb, lt1, lt2, shp, lgm, rw_bf, t_ws, feats);
  hipLaunchKernelGGL(k2_kernel, dim3(96), dim3(256), 0, stream, feats, spw_bf, sp_b,
                     ln_g, ln_b, scales);
  hipLaunchKernelGGL(k3_kernel, dim3(1024), dim3(256), 0, stream, scales, wts, on_g, on_b, out);
}

// Round 4
// 526.850 us; speedup vs baseline: 1.1061x; 1.0207x over previous
//
#include <hip/hip_runtime.h>
#include <math.h>

#define B_   1024
#define N_   200
#define NR_  208      // padded rows (13 x 16)
#define NT_  13
#define E_   256
#define R_   256
#define K6_  1536

typedef __attribute__((ext_vector_type(8))) short bf16x8;
typedef __attribute__((ext_vector_type(4))) float f32x4;

__device__ __forceinline__ unsigned short f2bf(float f) {
  unsigned int u = __float_as_uint(f);
  u += 0x7fffu + ((u >> 16) & 1u);          // RNE
  return (unsigned short)(u >> 16);
}

__device__ __forceinline__ float gelu_exact(float x) {
  return 0.5f * x * (1.f + erff(x * 0.70710678118654752f));
}

// ---------------- cast rel_w and sp_w to bf16 in ws ----------------
__global__ __launch_bounds__(256) void k_cast(const float* __restrict__ rel_w,
                                              const float* __restrict__ sp_w,
                                              unsigned short* __restrict__ rw_bf,
                                              unsigned short* __restrict__ spw_bf) {
  int idx = blockIdx.x * 256 + threadIdx.x;
  if (idx < E_ * R_) rw_bf[idx] = f2bf(rel_w[idx]);
  int j = idx - E_ * R_;
  if (j >= 0 && j < 3 * E_ * K6_) spw_bf[j] = f2bf(sp_w[j]);
}

// ------- k_prep: fused q_key -> (csq logits, wts) -> q_proj -> t  -------
// 256 blocks x 256 thr, 4 b's per block. All intermediates in LDS.
__global__ __launch_bounds__(256) void k_prep(
    const float* __restrict__ r_emb, const float* __restrict__ rel_w,
    const float* __restrict__ csq_w, const float* __restrict__ csq_b,
    const float* __restrict__ csl_w, const float* __restrict__ csl_b,
    const float* __restrict__ attn_w,
    float* __restrict__ t_ws, float* __restrict__ wts) {
  __shared__ __align__(16) float re[4][256];
  __shared__ __align__(16) float qk[4][256];
  __shared__ __align__(16) float sqs[4][256];
  __shared__ __align__(16) float qp[3][4][256];
  __shared__ float lg[4][3];
  int b0 = blockIdx.x * 4;
  int tid = threadIdx.x;
  int e = tid;
#pragma unroll
  for (int i = 0; i < 4; ++i)
    re[i][tid] = r_emb[(size_t)(b0 + i) * 256 + tid];
  __syncthreads();
  // q_key + csq (thread e streams rel_w row e and csq_w row e)
  {
    float qkv[4], sv[4];
#pragma unroll
    for (int i = 0; i < 4; ++i) { qkv[i] = 0.f; sv[i] = 0.f; }
    const float4* w4 = (const float4*)(rel_w) + (size_t)e * 64;
    const float4* c4 = (const float4*)(csq_w) + (size_t)e * 64;
    for (int r = 0; r < 64; ++r) {
      float4 w = w4[r];
      float4 c = c4[r];
#pragma unroll
      for (int i = 0; i < 4; ++i) {
        float4 x = ((const float4*)re[i])[r];
        qkv[i] += w.x * x.x + w.y * x.y + w.z * x.z + w.w * x.w;
        sv[i] += c.x * x.x + c.y * x.y + c.z * x.z + c.w * x.w;
      }
    }
    float cb = csq_b[e];
#pragma unroll
    for (int i = 0; i < 4; ++i) {
      qk[i][e] = qkv[i];
      sqs[i][e] = sv[i] + cb;
    }
  }
  __syncthreads();
  if (tid < 12) {
    int i = tid / 3, k = tid % 3;
    float acc = csl_b[k];
    for (int ee = 0; ee < 256; ++ee) acc += sqs[i][ee] * csl_w[k * 256 + ee];
    lg[i][k] = acc;
  }
  __syncthreads();
  if (tid < 4) {
    float l0 = lg[tid][0], l1 = lg[tid][1], l2 = lg[tid][2];
    float m = fmaxf(l0, fmaxf(l1, l2));
    float e0 = expf(l0 - m), e1 = expf(l1 - m), e2 = expf(l2 - m);
    float inv = 1.f / (e0 + e1 + e2);
    wts[(b0 + tid) * 4 + 0] = e0 * inv;
    wts[(b0 + tid) * 4 + 1] = e1 * inv;
    wts[(b0 + tid) * 4 + 2] = e2 * inv;
  }
  // q_proj (thread e streams attn_w[s] row e)
  {
    float qpv[3][4];
#pragma unroll
    for (int s = 0; s < 3; ++s)
#pragma unroll
      for (int i = 0; i < 4; ++i) qpv[s][i] = 0.f;
#pragma unroll
    for (int s = 0; s < 3; ++s) {
      const float4* a4 = (const float4*)(attn_w) + ((size_t)s * 256 + e) * 64;
      for (int r = 0; r < 64; ++r) {
        float4 w = a4[r];
#pragma unroll
        for (int i = 0; i < 4; ++i) {
          float4 x = ((const float4*)qk[i])[r];
          qpv[s][i] += w.x * x.x + w.y * x.y + w.z * x.z + w.w * x.w;
        }
      }
    }
    __syncthreads();
#pragma unroll
    for (int s = 0; s < 3; ++s)
#pragma unroll
      for (int i = 0; i < 4; ++i) qp[s][i][e] = qpv[s][i];
  }
  __syncthreads();
  // t[s,i,r] = sum_e qp[s,i,e]*rel_w[e,r] (thread r, coalesced rel_w rows)
  {
    int r = tid;
    float tacc[3][4];
#pragma unroll
    for (int s = 0; s < 3; ++s)
#pragma unroll
      for (int i = 0; i < 4; ++i) tacc[s][i] = 0.f;
    for (int e4 = 0; e4 < 64; ++e4) {
      float4 qv[3][4];
#pragma unroll
      for (int s = 0; s < 3; ++s)
#pragma unroll
        for (int i = 0; i < 4; ++i)
          qv[s][i] = ((const float4*)qp[s][i])[e4];   // broadcast
#pragma unroll
      for (int j = 0; j < 4; ++j) {
        float w = rel_w[(size_t)(e4 * 4 + j) * 256 + r];
#pragma unroll
        for (int s = 0; s < 3; ++s)
#pragma unroll
          for (int i = 0; i < 4; ++i) {
            float q = (j == 0) ? qv[s][i].x : (j == 1) ? qv[s][i].y
                      : (j == 2) ? qv[s][i].z : qv[s][i].w;
            tacc[s][i] = fmaf(q, w, tacc[s][i]);
          }
      }
    }
#pragma unroll
    for (int s = 0; s < 3; ++s)
#pragma unroll
      for (int i = 0; i < 4; ++i)
        t_ws[((size_t)s * B_ + b0 + i) * 256 + r] = tacc[s][i];
  }
}

// ------------- K1: single-pass fused msgs-GEMM + PNA stats + attention -------
// 1024 threads (16 waves), block = one b. Full 208x256 bf16 tile in LDS.
__global__ __launch_bounds__(1024, 4) void k1_main(
    const float* __restrict__ nb_rel, const float* __restrict__ delta_t,
    const unsigned char* __restrict__ hm_raw, const float* __restrict__ e_emb,
    const float* __restrict__ p_lt1, const float* __restrict__ p_lt2,
    const float* __restrict__ p_sh, const float* __restrict__ p_lgm,
    const unsigned short* __restrict__ rw_bf, const float* __restrict__ t_ws,
    unsigned short* __restrict__ feats) {
  __shared__ __align__(16) struct {
    unsigned int a[NR_ * 132];   // bf16 tile, row stride 264 bf16 (256 data + 8 pad)
    float araw[3][NR_];
    float c[3][NR_];
    float p[3][NR_];
    float nmeta[NR_][9];         // cm0,cm1,cm2,off,q0,q1,q2,maskf,pad
  } sm;
  int b = blockIdx.x;
  int tid = threadIdx.x;
  int lane = tid & 63, wave = tid >> 6;
  int row16 = lane & 15, quad = lane >> 4;

  // t fragments (lane owns r = lane*4 .. +3)
  float4 tf0 = *(const float4*)&t_ws[((size_t)0 * B_ + b) * 256 + lane * 4];
  float4 tf1 = *(const float4*)&t_ws[((size_t)1 * B_ + b) * 256 + lane * 4];
  float4 tf2 = *(const float4*)&t_ws[((size_t)2 * B_ + b) * 256 + lane * 4];

  // ---- mask dtype detection: probe first 1024 bytes ----
  int hasNZoff = 0, hasFP = 0;
  {
    unsigned char cc = hm_raw[tid];
    if ((tid & 3) != 0 && cc != 0) {
      hasNZoff = 1;
      if (cc == 0x3Fu || cc == 0x80u) hasFP = 1;
    }
  }
  int cntNZ = __syncthreads_count(hasNZoff);
  int cntFP = __syncthreads_count(hasFP);
  int mmode = (cntNZ == 0) ? 0 : (cntFP > 0 ? 2 : 1);  // 0=int32 1=bool 2=f32

  float tau1 = expf(p_lt1[0]);
  float tau2 = expf(p_lt2[0]) + tau1;
  float sharp = fminf(fmaxf(p_sh[0], 0.1f), 5.0f);
  float gamma = expf(p_lgm[0]);

  bool mk = false;
  if (tid < NR_) {
    float mf = 0.f, c0 = 0.f, c1 = 0.f, c2 = 0.f;
    if (tid < N_) {
      size_t mi = (size_t)b * N_ + tid;
      if (mmode == 0)      mk = ((const int*)hm_raw)[mi] != 0;
      else if (mmode == 1) mk = hm_raw[mi] != 0;
      else                 mk = ((const float*)hm_raw)[mi] != 0.f;
      float dt = delta_t[mi];
      mf = mk ? 1.f : 0.f;
      float decay = expf(-gamma * fmaxf(dt, 0.f));
      float wf = 1.f / (1.f + expf(sharp * (dt - tau1)));
      float wc = 1.f / (1.f + expf(-sharp * (dt - tau2)));
      float wm = fmaxf(1.f - wf - wc, 0.f);
      c0 = decay * wf; c1 = decay * wm; c2 = decay * wc;
    }
    sm.c[0][tid] = c0; sm.c[1][tid] = c1; sm.c[2][tid] = c2;
    sm.nmeta[tid][0] = mf * c0;
    sm.nmeta[tid][1] = mf * c1;
    sm.nmeta[tid][2] = mf * c2;
    sm.nmeta[tid][3] = mk ? 0.f : 1e4f;
    sm.nmeta[tid][7] = mf;
  }
  int cnt = __syncthreads_count(mk ? 1 : 0);
  float nvf = fmaxf((float)cnt, 1.f);
  bool allinv = (cnt == 0);

  // ---- staging + fused logit dots: wave w handles rows w, w+16, ... ----
  {
    const float* src = nb_rel + (size_t)b * N_ * 256;
    float4 x = *(const float4*)(src + (size_t)wave * 256 + lane * 4);
    for (int i = 0; i < NT_; ++i) {
      int ncur = i * 16 + wave;
      float4 xn;
      if (i < NT_ - 1) {
        int nn = (i + 1) * 16 + wave;
        int gn = (nn < N_) ? nn : (N_ - 1);
        xn = *(const float4*)(src + (size_t)gn * 256 + lane * 4);
      }
      float d0 = x.x * tf0.x + x.y * tf0.y + x.z * tf0.z + x.w * tf0.w;
      float d1 = x.x * tf1.x + x.y * tf1.y + x.z * tf1.z + x.w * tf1.w;
      float d2 = x.x * tf2.x + x.y * tf2.y + x.z * tf2.z + x.w * tf2.w;
#pragma unroll
      for (int o = 1; o < 64; o <<= 1) {
        d0 += __shfl_xor(d0, o, 64);
        d1 += __shfl_xor(d1, o, 64);
        d2 += __shfl_xor(d2, o, 64);
      }
      if (lane < 3) sm.araw[lane][ncur] = (lane == 0) ? d0 : ((lane == 1) ? d1 : d2);
      uint2 pk;
      pk.x = (unsigned int)f2bf(x.x) | ((unsigned int)f2bf(x.y) << 16);
      pk.y = (unsigned int)f2bf(x.z) | ((unsigned int)f2bf(x.w) << 16);
      *(uint2*)&sm.a[ncur * 132 + lane * 2] = pk;
      x = xn;
    }
  }

  // B-fragment preload (wave owns 16 e-cols)
  bf16x8 bfr[8];
  {
    int e = wave * 16 + row16;
#pragma unroll
    for (int ks = 0; ks < 8; ++ks)
      bfr[ks] = *(const bf16x8*)(rw_bf + (size_t)e * 256 + ks * 32 + quad * 8);
  }
  __syncthreads();

  // ---- logits from raw dots ----
  if (tid < NR_) {
    float l0 = -1e30f, l1 = -1e30f, l2 = -1e30f;
    if (tid < N_) {
      bool mkk = sm.nmeta[tid][7] > 0.5f;
      l0 = sm.c[0][tid] * sm.araw[0][tid] * 0.0625f;
      l1 = sm.c[1][tid] * sm.araw[1][tid] * 0.0625f;
      l2 = sm.c[2][tid] * sm.araw[2][tid] * 0.0625f;
      l0 = mkk ? l0 : -1e4f; l1 = mkk ? l1 : -1e4f; l2 = mkk ? l2 : -1e4f;
      if (allinv) { l0 = 0.f; l1 = 0.f; l2 = 0.f; }
    }
    sm.p[0][tid] = l0; sm.p[1][tid] = l1; sm.p[2][tid] = l2;
  }
  __syncthreads();

  // ---- softmax (waves 0-2) + e_emb tail copy (wave 3) ----
  if (wave < 3) {
    int s = wave;
    float m = -1e30f;
    for (int n = lane; n < NR_; n += 64) m = fmaxf(m, sm.p[s][n]);
#pragma unroll
    for (int o = 32; o >= 1; o >>= 1) m = fmaxf(m, __shfl_xor(m, o, 64));
    float ssum = 0.f;
    for (int n = lane; n < NR_; n += 64) ssum += expf(sm.p[s][n] - m);
#pragma unroll
    for (int o = 32; o >= 1; o >>= 1) ssum += __shfl_xor(ssum, o, 64);
    float inv = 1.f / ssum;
    for (int n = lane; n < NR_; n += 64) {
      float pv = expf(sm.p[s][n] - m) * inv;
      sm.nmeta[n][4 + s] = pv * sm.c[s][n];
    }
  } else if (wave == 3) {
    for (int i = lane; i < 256; i += 64) {
      unsigned short v = f2bf(e_emb[(size_t)b * 256 + i]);
      feats[((size_t)0 * B_ + b) * K6_ + 1280 + i] = v;
      feats[((size_t)1 * B_ + b) * K6_ + 1280 + i] = v;
      feats[((size_t)2 * B_ + b) * K6_ + 1280 + i] = v;
    }
  }
  __syncthreads();

  // ---- MFMA GEMM over 13 n-tiles + register stats (wave owns 16 e-cols) ----
  float s_mean[3], s_mx[3], s_mn[3], s_sq[3], s_av[3];
#pragma unroll
  for (int s = 0; s < 3; ++s) {
    s_mean[s] = 0.f; s_mx[s] = -1e30f; s_mn[s] = 1e30f;
    s_sq[s] = 0.f; s_av[s] = 0.f;
  }

  for (int nt = 0; nt < NT_; ++nt) {
    f32x4 acc;
#pragma unroll
    for (int cc = 0; cc < 4; ++cc) acc[cc] = 0.f;
#pragma unroll
    for (int ks = 0; ks < 8; ++ks) {
      bf16x8 af = *(const bf16x8*)&sm.a[(nt * 16 + row16) * 132 + ks * 16 + quad * 4];
      acc = __builtin_amdgcn_mfma_f32_16x16x32_bf16(af, bfr[ks], acc, 0, 0, 0);
    }
    int nb = nt * 16 + quad * 4;
#pragma unroll
    for (int rg = 0; rg < 4; ++rg) {
      int n = nb + rg;
      float cm0 = sm.nmeta[n][0], cm1 = sm.nmeta[n][1], cm2 = sm.nmeta[n][2];
      float off = sm.nmeta[n][3];
      float q0 = sm.nmeta[n][4], q1 = sm.nmeta[n][5], q2 = sm.nmeta[n][6];
      float m = acc[rg];
      float cmv[3] = {cm0, cm1, cm2};
      float qv[3] = {q0, q1, q2};
#pragma unroll
      for (int s = 0; s < 3; ++s) {
        float vm = cmv[s] * m;
        s_mean[s] += vm;
        s_mx[s] = fmaxf(s_mx[s], vm);
        s_mn[s] = fminf(s_mn[s], fmaf(cmv[s], m, off));
        float cv = fminf(fmaxf(vm, -10.f), 10.f);
        s_sq[s] = fmaf(cv, cv, s_sq[s]);
        s_av[s] = fmaf(qv[s], m, s_av[s]);
      }
    }
  }

  // ---- reduce across quads, write feats (bf16) ----
#pragma unroll
  for (int s = 0; s < 3; ++s) {
    float vmean = s_mean[s];
    vmean += __shfl_xor(vmean, 16, 64); vmean += __shfl_xor(vmean, 32, 64);
    float vmx = s_mx[s];
    vmx = fmaxf(vmx, __shfl_xor(vmx, 16, 64)); vmx = fmaxf(vmx, __shfl_xor(vmx, 32, 64));
    float vmn = s_mn[s];
    vmn = fminf(vmn, __shfl_xor(vmn, 16, 64)); vmn = fminf(vmn, __shfl_xor(vmn, 32, 64));
    float vsq = s_sq[s];
    vsq += __shfl_xor(vsq, 16, 64); vsq += __shfl_xor(vsq, 32, 64);
    float vav = s_av[s];
    vav += __shfl_xor(vav, 16, 64); vav += __shfl_xor(vav, 32, 64);
    if (lane < 16) {
      int e = wave * 16 + lane;
      size_t base = ((size_t)s * B_ + b) * K6_;
      float meanv = vmean / nvf;
      float stdv = sqrtf(fmaxf(vsq / nvf - meanv * meanv, 1e-6f));
      float mnv = fminf(fmaxf(vmn, -1e4f), 1e4f);
      feats[base + e] = f2bf(meanv);
      feats[base + 256 + e] = f2bf(vmx);
      feats[base + 512 + e] = f2bf(mnv);
      feats[base + 768 + e] = f2bf(stdv);
      feats[base + 1024 + e] = f2bf(vav);
    }
  }
}

// ------- K2: h = feats(bf16) @ sp_w^T + bias -> hbuf (pre-LN, fp32) -------
// grid 384: (3 s) x (64 b-tiles of 16) x (2 e-halves of 128)
__global__ __launch_bounds__(256) void k2_kernel(
    const unsigned short* __restrict__ feats, const unsigned short* __restrict__ spw_bf,
    const float* __restrict__ sp_b, float* __restrict__ hbuf) {
  __shared__ __align__(16) unsigned int a[16 * 132];
  int id = blockIdx.x;
  int s = id >> 7;
  int rem = id & 127;
  int b0 = (rem >> 1) * 16;
  int e0 = (rem & 1) * 128;
  int tid = threadIdx.x, lane = tid & 63, wave = tid >> 6;
  int row16 = lane & 15, quad = lane >> 4;
  f32x4 acc[2];
#pragma unroll
  for (int t = 0; t < 2; ++t)
#pragma unroll
    for (int cc = 0; cc < 4; ++cc) acc[t][cc] = 0.f;

  for (int kc = 0; kc < 6; ++kc) {
    __syncthreads();
    for (int j = tid; j < 512; j += 256) {
      int rw = j >> 5, ck = j & 31;
      bf16x8 v = *(const bf16x8*)(feats + ((size_t)s * B_ + b0 + rw) * K6_ + kc * 256 + ck * 8);
      *(bf16x8*)((unsigned short*)&a[rw * 132] + ck * 8) = v;
    }
    __syncthreads();
#pragma unroll
    for (int ks = 0; ks < 8; ++ks) {
      bf16x8 af = *(const bf16x8*)&a[row16 * 132 + ks * 16 + quad * 4];
#pragma unroll
      for (int t = 0; t < 2; ++t) {
        int e = e0 + wave * 32 + t * 16 + row16;
        bf16x8 bfr = *(const bf16x8*)(spw_bf + ((size_t)s * E_ + e) * K6_ + kc * 256 + ks * 32 + quad * 8);
        acc[t] = __builtin_amdgcn_mfma_f32_16x16x32_bf16(af, bfr, acc[t], 0, 0, 0);
      }
    }
  }
#pragma unroll
  for (int t = 0; t < 2; ++t) {
    int e = e0 + wave * 32 + t * 16 + row16;
    float bias = sp_b[s * 256 + e];
#pragma unroll
    for (int rg = 0; rg < 4; ++rg) {
      int rw = quad * 4 + rg;
      hbuf[((size_t)s * B_ + b0 + rw) * 256 + e] = acc[t][rg] + bias;
    }
  }
}

// ------- K3: per b: for each s LN+gelu, weighted sum, final LN -> out -------
__global__ __launch_bounds__(256) void k3_kernel(
    const float* __restrict__ hbuf, const float* __restrict__ wts,
    const float* __restrict__ ln_g, const float* __restrict__ ln_b,
    const float* __restrict__ on_g, const float* __restrict__ on_b,
    float* __restrict__ out) {
  __shared__ float rs[4], rq[4];
  int b = blockIdx.x, tid = threadIdx.x, lane = tid & 63, wave = tid >> 6;
  float o = 0.f;
#pragma unroll
  for (int s = 0; s < 3; ++s) {
    float h = hbuf[((size_t)s * B_ + b) * 256 + tid];
    float sum = h, sq = h * h;
#pragma unroll
    for (int off = 32; off >= 1; off >>= 1) {
      sum += __shfl_xor(sum, off, 64);
      sq += __shfl_xor(sq, off, 64);
    }
    if (lane == 0) { rs[wave] = sum; rq[wave] = sq; }
    __syncthreads();
    float ts = rs[0] + rs[1] + rs[2] + rs[3];
    float tq = rq[0] + rq[1] + rq[2] + rq[3];
    __syncthreads();
    float mu = ts * (1.f / 256.f);
    float var = tq * (1.f / 256.f) - mu * mu;
    float rstd = rsqrtf(var + 1e-5f);
    float v = (h - mu) * rstd * ln_g[s * 256 + tid] + ln_b[s * 256 + tid];
    o += wts[b * 4 + s] * gelu_exact(v);
  }
  float sum = o, sq = o * o;
#pragma unroll
  for (int off = 32; off >= 1; off >>= 1) {
    sum += __shfl_xor(sum, off, 64);
    sq += __shfl_xor(sq, off, 64);
  }
  if (lane == 0) { rs[wave] = sum; rq[wave] = sq; }
  __syncthreads();
  float ts = rs[0] + rs[1] + rs[2] + rs[3];
  float tq = rq[0] + rq[1] + rq[2] + rq[3];
  float mu = ts * (1.f / 256.f);
  float var = tq * (1.f / 256.f) - mu * mu;
  float rstd = rsqrtf(var + 1e-5f);
  out[(size_t)b * 256 + tid] = (o - mu) * rstd * on_g[tid] + on_b[tid];
}

extern "C" void kernel_launch(void* const* d_in, const int* in_sizes, int n_in,
                              void* d_out, int out_size, void* d_ws, size_t ws_size,
                              hipStream_t stream) {
  const float* e_emb   = (const float*)d_in[0];
  const float* nb_rel  = (const float*)d_in[1];
  const float* delta_t = (const float*)d_in[2];
  const float* r_emb   = (const float*)d_in[3];
  const unsigned char* hist_mask = (const unsigned char*)d_in[4]; // dtype auto-detected
  const float* rel_w   = (const float*)d_in[5];
  const float* lt1     = (const float*)d_in[6];
  const float* lt2     = (const float*)d_in[7];
  const float* shp     = (const float*)d_in[8];
  const float* lgm     = (const float*)d_in[9];
  const float* attn_w  = (const float*)d_in[10];
  const float* sp_w    = (const float*)d_in[11];
  const float* sp_b    = (const float*)d_in[12];
  const float* ln_g    = (const float*)d_in[13];
  const float* ln_b    = (const float*)d_in[14];
  const float* csq_w   = (const float*)d_in[15];
  const float* csq_b   = (const float*)d_in[16];
  const float* csl_w   = (const float*)d_in[17];
  const float* csl_b   = (const float*)d_in[18];
  const float* on_g    = (const float*)d_in[19];
  const float* on_b    = (const float*)d_in[20];
  float* out = (float*)d_out;

  char* ws = (char*)d_ws;
  unsigned short* rw_bf  = (unsigned short*)(ws + 0);         // 131072 B
  unsigned short* spw_bf = (unsigned short*)(ws + 131072);    // 2359296 B
  float* t_ws   = (float*)(ws + 2490368);                     // 3 MB
  float* wts    = (float*)(ws + 5636096);                     // 16 KB
  unsigned short* feats = (unsigned short*)(ws + 5652480);    // 9.44 MB (bf16)
  float* hbuf   = (float*)(ws + 15089664);                    // 3 MB (total ~18.2 MB)

  hipLaunchKernelGGL(k_cast, dim3(4864), dim3(256), 0, stream, rel_w, sp_w, rw_bf, spw_bf);
  hipLaunchKernelGGL(k_prep, dim3(256), dim3(256), 0, stream, r_emb, rel_w, csq_w, csq_b,
                     csl_w, csl_b, attn_w, t_ws, wts);
  hipLaunchKernelGGL(k1_main, dim3(1024), dim3(1024), 0, stream, nb_rel, delta_t, hist_mask,
                     e_emb, lt1, lt2, shp, lgm, rw_bf, t_ws, feats);
  hipLaunchKernelGGL(k2_kernel, dim3(384), dim3(256), 0, stream, feats, spw_bf, sp_b, hbuf);
  hipLaunchKernelGGL(k3_kernel, dim3(1024), dim3(256), 0, stream, hbuf, wts, ln_g, ln_b,
                     on_g, on_b, out);
}